// Round 10
// baseline (65.192 us; speedup 1.0000x reference)
//
#include <hip/hip_runtime.h>

#define B_ 4
#define T_ 8
#define N_ 256
#define F_ 16
#define D_ 64
#define NP (D_/2)       // 32 pairs per row
#define CHUNK 8
#define NCH (N_/CHUNK)  // 32 -> main grid = 1024 blocks
#define REP 4           // diagnostic multiplier (idempotent) to surface counters

#define SC 2.8853900817779268f        // 2*log2(e): exp2(SC*x) = e^{2x}
#define LOG2E 1.4426950408889634f

typedef __attribute__((ext_vector_type(16))) float f32x16;

__device__ __forceinline__ float fast_exp2(float x) { return __builtin_amdgcn_exp2f(x); }
__device__ __forceinline__ float fast_rcp(float x)  { return __builtin_amdgcn_rcpf(x); }

// ---------------- prologue ----------------
// Eq[row][d] = exp2(SC*(q Wq + bq)_d)        (row-major)
// EkT[bt][d][m] = exp2(SC*(k Wk + bk)_d)     (transposed -> coalesced main loads)
__global__ __launch_bounds__(256)
void tattn_proj_kernel(const float* __restrict__ query,
                       const float* __restrict__ keys,
                       const float* __restrict__ Wq, const float* __restrict__ bq,
                       const float* __restrict__ Wk, const float* __restrict__ bk,
                       float* __restrict__ Eq, float* __restrict__ EkT)
{
    const int tid = threadIdx.x;
    const int row = blockIdx.x * 4 + (tid >> 6);   // 4 rows (waves) per block
    const int j   = tid & 63;
    const int NQ  = B_ * N_;

    if (row < NQ) {                                // wave-uniform branch
        const float* in = query + (size_t)row * F_;
        float acc = bq[j];
        #pragma unroll
        for (int f = 0; f < F_; ++f) acc = fmaf(in[f], Wq[f * D_ + j], acc);
        Eq[(size_t)row * D_ + j] = fast_exp2(acc * SC);
    } else {
        const int r  = row - NQ;                   // r = bt*N + n
        const int bt = r >> 8, n = r & (N_ - 1);
        const float* in = keys + (size_t)r * F_;
        float acc = bk[j];
        #pragma unroll
        for (int f = 0; f < F_; ++f) acc = fmaf(in[f], Wk[f * D_ + j], acc);
        EkT[((size_t)bt * D_ + j) * N_ + n] = fast_exp2(acc * SC);
    }
}

// ---------------- main (x REP for counter visibility) ----------------
__global__ __launch_bounds__(256, 3)
void tattn_main_kernel(const float* __restrict__ Eq,
                       const float* __restrict__ EkT,
                       const float* __restrict__ wt,
                       float* __restrict__ out)
{
    __shared__ float pbuf[CHUNK][N_];   // 8 KB
    __shared__ float wls[D_];
    __shared__ float totL[CHUNK];

    const int tid = threadIdx.x;
    const int bid = blockIdx.x;
    const int ch  = bid % NCH;
    const int t   = (bid / NCH) % T_;
    const int b   = bid / (NCH * T_);
    const int n0  = ch * CHUNK;
    const int bt  = b * T_ + t;

    if (tid < D_) wls[tid] = 2.0f * wt[tid];

    // Ek column for key m=tid: 64 coalesced wave loads (loop-invariant wrt rep)
    float kreg[D_];
    {
        const float* kp = EkT + (size_t)bt * D_ * N_ + tid;
        #pragma unroll
        for (int d = 0; d < D_; ++d) kreg[d] = kp[(size_t)d * N_];
    }
    __syncthreads();

    float wv[D_];
    #pragma unroll
    for (int d = 0; d < D_; d += 4) {
        float4 v = *reinterpret_cast<const float4*>(&wls[d]);
        wv[d] = v.x; wv[d+1] = v.y; wv[d+2] = v.z; wv[d+3] = v.w;
    }
    float Wsum = 0.f;
    #pragma unroll
    for (int d = 0; d < D_; ++d) Wsum += wv[d];
    Wsum *= 0.5f;

    const int lane = tid & 63;
    const int wid  = tid >> 6;
    const size_t obase = ((size_t)(bt * N_ + n0)) * N_ + tid;

    #pragma unroll 1
    for (int rep = 0; rep < REP; ++rep) {          // idempotent repeat (diagnostic)
        const float* eqrow = Eq + ((size_t)(b * N_ + n0)) * D_;

        #pragma unroll 1
        for (int nn = 0; nn < CHUNK; ++nn) {
            f32x16 e0, e1, e2, e3;
            asm volatile("s_load_dwordx16 %0, %4, 0x0\n\t"
                         "s_load_dwordx16 %1, %4, 0x40\n\t"
                         "s_load_dwordx16 %2, %4, 0x80\n\t"
                         "s_load_dwordx16 %3, %4, 0xc0"
                         : "=&s"(e0), "=&s"(e1), "=&s"(e2), "=&s"(e3)
                         : "s"(eqrow));
            asm volatile("s_waitcnt lgkmcnt(0)"
                         : "+s"(e0), "+s"(e1), "+s"(e2), "+s"(e3));
            __builtin_amdgcn_sched_barrier(0);

            float a0 = 0.f, a1 = 0.f, a2 = 0.f, a3 = 0.f;
            #pragma unroll
            for (int pr = 0; pr < NP; ++pr) {
                float eqa, eqb;
                if      (pr <  8) { eqa = e0[2*pr];      eqb = e0[2*pr+1];  }
                else if (pr < 16) { eqa = e1[2*pr-16];   eqb = e1[2*pr-15]; }
                else if (pr < 24) { eqa = e2[2*pr-32];   eqb = e2[2*pr-31]; }
                else              { eqa = e3[2*pr-48];   eqb = e3[2*pr-47]; }
                float pA = fmaf(eqa, kreg[2*pr+0], 1.0f);
                float qA = fmaf(eqb, kreg[2*pr+1], 1.0f);
                float nA = fmaf(wv[2*pr+1], pA, wv[2*pr] * qA);
                float r  = fast_rcp(pA * qA);
                if      ((pr & 3) == 0) a0 = fmaf(nA, r, a0);
                else if ((pr & 3) == 1) a1 = fmaf(nA, r, a1);
                else if ((pr & 3) == 2) a2 = fmaf(nA, r, a2);
                else                    a3 = fmaf(nA, r, a3);
            }
            float score = Wsum - ((a0 + a1) + (a2 + a3));
            pbuf[nn][tid] = fast_exp2(score * LOG2E);
            eqrow += D_;
        }
        __syncthreads();

        #pragma unroll
        for (int rr = 0; rr < 2; ++rr) {
            const int row = wid * 2 + rr;
            float4 v = *reinterpret_cast<const float4*>(&pbuf[row][lane * 4]);
            float s = (v.x + v.y) + (v.z + v.w);
            #pragma unroll
            for (int off = 32; off >= 1; off >>= 1) s += __shfl_xor(s, off);
            if (lane == 0) totL[row] = s;
        }
        __syncthreads();

        #pragma unroll
        for (int nn = 0; nn < CHUNK; ++nn)
            out[obase + (size_t)nn * N_] = pbuf[nn][tid] * fast_rcp(totL[nn]);
        __syncthreads();                           // protect pbuf reuse next rep
    }
}

extern "C" void kernel_launch(void* const* d_in, const int* in_sizes, int n_in,
                              void* d_out, int out_size, void* d_ws, size_t ws_size,
                              hipStream_t stream) {
    const float* query = (const float*)d_in[0];
    const float* keys  = (const float*)d_in[1];
    const float* Wq    = (const float*)d_in[2];
    const float* bq    = (const float*)d_in[3];
    const float* Wk    = (const float*)d_in[4];
    const float* bk    = (const float*)d_in[5];
    const float* wt    = (const float*)d_in[6];
    float* out = (float*)d_out;

    float* Eq  = (float*)d_ws;                         // B*N*D   floats (256 KB)
    float* EkT = Eq + (size_t)B_ * N_ * D_;            // B*T*D*N floats (2 MB)

    const int rows = B_ * N_ + B_ * T_ * N_;           // 9216, 4 rows/block
    hipLaunchKernelGGL(tattn_proj_kernel, dim3(rows / 4), dim3(256), 0, stream,
                       query, keys, Wq, bq, Wk, bk, Eq, EkT);

    hipLaunchKernelGGL(tattn_main_kernel, dim3(B_ * T_ * NCH), dim3(256), 0, stream,
                       Eq, EkT, wt, out);
}

// Round 11
// 43.760 us; speedup vs baseline: 1.4898x; 1.4898x over previous
//
#include <hip/hip_runtime.h>

#define B_ 4
#define T_ 8
#define N_ 256
#define F_ 16
#define D_ 64
#define NP 32           // pairs per row
#define CHUNK 8
#define NCH (N_/CHUNK)  // 32 -> main grid = 1024 blocks = 4/CU

#define SC 2.8853900817779268f        // 2*log2(e): exp2(SC*x) = e^{2x}
#define LOG2E 1.4426950408889634f

typedef __attribute__((ext_vector_type(16))) float f32x16;

__device__ __forceinline__ float fast_exp2(float x) { return __builtin_amdgcn_exp2f(x); }
__device__ __forceinline__ float fast_rcp(float x)  { return __builtin_amdgcn_rcpf(x); }

// ---------------- prologue ----------------
// q-rows -> StreamQ[row][pair pr] = (eqa, eqb, A, B)
//   eqa=exp2(SC*qproj_{2pr}), eqb=..._{2pr+1}, A=2*L2E*w_{2pr+1}*eqa, B=2*L2E*w_{2pr}*eqb
// k-rows -> EkT[bt][d][m] (transposed -> coalesced main loads)
__global__ __launch_bounds__(256)
void tattn_proj_kernel(const float* __restrict__ query,
                       const float* __restrict__ keys,
                       const float* __restrict__ Wq, const float* __restrict__ bq,
                       const float* __restrict__ Wk, const float* __restrict__ bk,
                       const float* __restrict__ wt,
                       float* __restrict__ StreamQ, float* __restrict__ EkT)
{
    const int tid = threadIdx.x;
    const int row = blockIdx.x * 4 + (tid >> 6);   // 4 rows (waves) per block
    const int j   = tid & 63;
    const int NQ  = B_ * N_;

    if (row < NQ) {                                // wave-uniform branch
        const float* in = query + (size_t)row * F_;
        float acc = bq[j];
        #pragma unroll
        for (int f = 0; f < F_; ++f) acc = fmaf(in[f], Wq[f * D_ + j], acc);
        float eq = fast_exp2(acc * SC);
        float ab = 2.0f * LOG2E * wt[j ^ 1] * eq;  // A (even j) or B (odd j)
        float* qs = StreamQ + (size_t)row * (4 * NP) + 4 * (j >> 1);
        if ((j & 1) == 0) { qs[0] = eq; qs[2] = ab; }
        else              { qs[1] = eq; qs[3] = ab; }
    } else {
        const int r  = row - NQ;                   // r = bt*N + n
        const int bt = r >> 8, n = r & (N_ - 1);
        const float* in = keys + (size_t)r * F_;
        float acc = bk[j];
        #pragma unroll
        for (int f = 0; f < F_; ++f) acc = fmaf(in[f], Wk[f * D_ + j], acc);
        EkT[((size_t)bt * D_ + j) * N_ + n] = fast_exp2(acc * SC);
    }
}

// ---------------- main ----------------
// L2E*score(n,m) = WsumL - sum_quads (n01*d23 + n23*d01) * rcp(d01*d23)
//   n01 = C[2qd] + A0*ek0 + B0*ek1 (L2E-scaled), d01 = D0*D1, D = 1 + eq*ek
// Stream via s_load_dwordx16 (2 batches/row). 16 rcp/row. Hot loop: no LDS reads, no VMEM.
__global__ __launch_bounds__(256, 4)
void tattn_main_kernel(const float* __restrict__ StreamQ,
                       const float* __restrict__ EkT,
                       const float* __restrict__ wt,
                       float* __restrict__ out)
{
    __shared__ float pbuf[CHUNK][N_];   // 8 KB
    __shared__ float totL[CHUNK];

    const int tid = threadIdx.x;
    const int bid = blockIdx.x;
    const int ch  = bid % NCH;
    const int t   = (bid / NCH) % T_;
    const int b   = bid / (NCH * T_);
    const int n0  = ch * CHUNK;
    const int bt  = b * T_ + t;

    // Ek column for key m=tid: 64 coalesced wave loads
    float kreg[D_];
    {
        const float* kp = EkT + (size_t)bt * D_ * N_ + tid;
        #pragma unroll
        for (int d = 0; d < D_; ++d) kreg[d] = kp[(size_t)d * N_];
    }

    // C[pr] = 2*L2E*(w0+w1); WsumL = L2E*sum(wt) = 0.5*sum(C)
    float Cv[NP];
    float WsumL = 0.f;
    #pragma unroll
    for (int pr = 0; pr < NP; ++pr) {
        float2 w2 = ((const float2*)wt)[pr];
        Cv[pr] = 2.0f * LOG2E * (w2.x + w2.y);
        WsumL += Cv[pr];
    }
    WsumL *= 0.5f;

    const char* srow = (const char*)(StreamQ + (size_t)(b * N_ + n0) * (4 * NP)); // 512 B/row

#define QUAD(EV, QD, BASE)                                                     \
    {                                                                          \
        float D0 = fmaf(EV[(BASE)+0], kreg[4*(QD)+0], 1.0f);                   \
        float D1 = fmaf(EV[(BASE)+1], kreg[4*(QD)+1], 1.0f);                   \
        float D2 = fmaf(EV[(BASE)+4], kreg[4*(QD)+2], 1.0f);                   \
        float D3 = fmaf(EV[(BASE)+5], kreg[4*(QD)+3], 1.0f);                   \
        float n01 = fmaf(EV[(BASE)+2], kreg[4*(QD)+0],                         \
                         fmaf(EV[(BASE)+3], kreg[4*(QD)+1], Cv[2*(QD)+0]));    \
        float n23 = fmaf(EV[(BASE)+6], kreg[4*(QD)+2],                         \
                         fmaf(EV[(BASE)+7], kreg[4*(QD)+3], Cv[2*(QD)+1]));    \
        float d01 = D0 * D1;                                                   \
        float d23 = D2 * D3;                                                   \
        float Nn  = fmaf(n01, d23, n23 * d01);                                 \
        float Dq  = d01 * d23;                                                 \
        acc[(QD) & 3] = fmaf(Nn, fast_rcp(Dq), acc[(QD) & 3]);                 \
    }

    #pragma unroll 1
    for (int nn = 0; nn < CHUNK; ++nn) {
        float acc[4] = {0.f, 0.f, 0.f, 0.f};

        {   // batch 0: pairs 0..15 -> quads 0..7
            f32x16 e0, e1, e2, e3;
            asm volatile("s_load_dwordx16 %0, %4, 0x0\n\t"
                         "s_load_dwordx16 %1, %4, 0x40\n\t"
                         "s_load_dwordx16 %2, %4, 0x80\n\t"
                         "s_load_dwordx16 %3, %4, 0xc0"
                         : "=&s"(e0), "=&s"(e1), "=&s"(e2), "=&s"(e3)
                         : "s"(srow));
            asm volatile("s_waitcnt lgkmcnt(0)"
                         : "+s"(e0), "+s"(e1), "+s"(e2), "+s"(e3));
            __builtin_amdgcn_sched_barrier(0);
            QUAD(e0, 0, 0) QUAD(e0, 1, 8) QUAD(e1, 2, 0) QUAD(e1, 3, 8)
            QUAD(e2, 4, 0) QUAD(e2, 5, 8) QUAD(e3, 6, 0) QUAD(e3, 7, 8)
        }
        {   // batch 1: pairs 16..31 -> quads 8..15
            f32x16 e0, e1, e2, e3;
            asm volatile("s_load_dwordx16 %0, %4, 0x100\n\t"
                         "s_load_dwordx16 %1, %4, 0x140\n\t"
                         "s_load_dwordx16 %2, %4, 0x180\n\t"
                         "s_load_dwordx16 %3, %4, 0x1c0"
                         : "=&s"(e0), "=&s"(e1), "=&s"(e2), "=&s"(e3)
                         : "s"(srow));
            asm volatile("s_waitcnt lgkmcnt(0)"
                         : "+s"(e0), "+s"(e1), "+s"(e2), "+s"(e3));
            __builtin_amdgcn_sched_barrier(0);
            QUAD(e0,  8, 0) QUAD(e0,  9, 8) QUAD(e1, 10, 0) QUAD(e1, 11, 8)
            QUAD(e2, 12, 0) QUAD(e2, 13, 8) QUAD(e3, 14, 0) QUAD(e3, 15, 8)
        }

        // p = exp2(L2E*score); |score| <= sum|wt| ~ 8 -> no max subtraction
        pbuf[nn][tid] = fast_exp2(WsumL - ((acc[0] + acc[1]) + (acc[2] + acc[3])));
        srow += 4 * NP * sizeof(float);
    }
#undef QUAD
    __syncthreads();

    // per-row totals: wave w reduces rows 2w, 2w+1 (outside hot loop)
    const int lane = tid & 63;
    const int wid  = tid >> 6;
    #pragma unroll
    for (int rr = 0; rr < 2; ++rr) {
        const int row = wid * 2 + rr;
        float4 v = *reinterpret_cast<const float4*>(&pbuf[row][lane * 4]);
        float s = (v.x + v.y) + (v.z + v.w);
        #pragma unroll
        for (int off = 32; off >= 1; off >>= 1) s += __shfl_xor(s, off);
        if (lane == 0) totL[row] = s;
    }
    __syncthreads();

    const size_t obase = ((size_t)(bt * N_ + n0)) * N_ + tid;
    #pragma unroll
    for (int nn = 0; nn < CHUNK; ++nn)
        out[obase + (size_t)nn * N_] = pbuf[nn][tid] * fast_rcp(totL[nn]);
}

extern "C" void kernel_launch(void* const* d_in, const int* in_sizes, int n_in,
                              void* d_out, int out_size, void* d_ws, size_t ws_size,
                              hipStream_t stream) {
    const float* query = (const float*)d_in[0];
    const float* keys  = (const float*)d_in[1];
    const float* Wq    = (const float*)d_in[2];
    const float* bq    = (const float*)d_in[3];
    const float* Wk    = (const float*)d_in[4];
    const float* bk    = (const float*)d_in[5];
    const float* wt    = (const float*)d_in[6];
    float* out = (float*)d_out;

    float* StreamQ = (float*)d_ws;                         // B*N*128 floats = 512 KB
    float* EkT     = StreamQ + (size_t)B_ * N_ * 4 * NP;   // B*T*D*N floats = 2 MB

    const int rows = B_ * N_ + B_ * T_ * N_;               // 9216, 4 rows/block
    hipLaunchKernelGGL(tattn_proj_kernel, dim3(rows / 4), dim3(256), 0, stream,
                       query, keys, Wq, bq, Wk, bk, wt, StreamQ, EkT);

    hipLaunchKernelGGL(tattn_main_kernel, dim3(B_ * T_ * NCH), dim3(256), 0, stream,
                       StreamQ, EkT, wt, out);
}